// Round 3
// baseline (1478.787 us; speedup 1.0000x reference)
//
#include <hip/hip_runtime.h>
#include <math.h>

#define Hh 256
#define Ww 256
#define HW 65536
#define Bn 4
#define Cdim 60
#define Ce 120
#define NPIX (Bn*HW)

typedef const float* fp;

// ---------------- LFE stage 1: y1 = gelu(conv1x1(shift(src), w0, b0)) ----------------
__global__ __launch_bounds__(256) void k_lfe1(const float* __restrict__ X, float* __restrict__ Y1,
                                              fp w0, fp b0){
  __shared__ __align__(16) float wL[Ce*Cdim];
  __shared__ float bL[Ce];
  int tid = threadIdx.x;
  for (int i = tid; i < Ce*Cdim; i += 256) wL[i] = w0[i];
  if (tid < Ce) bL[tid] = b0[tid];
  __syncthreads();
  int p = blockIdx.x*256 + tid;
  int b = p >> 16; int hw = p & 65535; int h = hw >> 8; int w = hw & 255;
  const float* Xb = X + (size_t)b*(Cdim*HW);
  float xs[Cdim];
  #pragma unroll
  for (int c = 0; c < Cdim; c++){
    int grp = c / 12;
    int hh = h, ww = w; bool ok = true;
    if (grp == 0){ ww = w+1; ok = (ww < Ww); }
    else if (grp == 1){ ww = w-1; ok = (ww >= 0); }
    else if (grp == 2){ hh = h+1; ok = (hh < Hh); }
    else if (grp == 3){ hh = h-1; ok = (hh >= 0); }
    xs[c] = ok ? Xb[c*HW + hh*Ww + ww] : 0.f;
  }
  const float4* wL4 = (const float4*)wL;
  float* Yb = Y1 + (size_t)b*(Ce*HW) + h*Ww + w;
  #pragma unroll 2
  for (int o = 0; o < Ce; o++){
    float acc = bL[o];
    #pragma unroll
    for (int c4 = 0; c4 < 15; c4++){
      float4 wv = wL4[o*15 + c4];
      acc += wv.x*xs[4*c4] + wv.y*xs[4*c4+1] + wv.z*xs[4*c4+2] + wv.w*xs[4*c4+3];
    }
    float g = 0.5f*acc*(1.f + erff(acc*0.70710678118654752f)); // exact gelu
    Yb[o*HW] = g;
  }
}

// ---------------- LFE stage 2: X = conv1x1(shift(y1), w1, b1) + resid ----------------
__global__ __launch_bounds__(256) void k_lfe2(const float* __restrict__ Y1,
                                              const float* __restrict__ R,
                                              float* __restrict__ X,
                                              fp w1, fp b1){
  __shared__ __align__(16) float wT[Ce*Cdim];  // transposed: [e][c]
  __shared__ float bL[Cdim];
  int tid = threadIdx.x;
  for (int i = tid; i < Ce*Cdim; i += 256){
    int e = i / Cdim, c = i - e*Cdim;
    wT[i] = w1[c*Ce + e];
  }
  if (tid < Cdim) bL[tid] = b1[tid];
  __syncthreads();
  int p = blockIdx.x*256 + tid;
  int b = p >> 16; int hw = p & 65535; int h = hw >> 8; int w = hw & 255;
  const float* Yb = Y1 + (size_t)b*(Ce*HW);
  float acc[Cdim];
  #pragma unroll
  for (int c = 0; c < Cdim; c++) acc[c] = 0.f;
  const float4* wT4 = (const float4*)wT;
  #pragma unroll 1
  for (int e = 0; e < Ce; e++){
    int grp = e / 24;
    int hh = h, ww = w; bool ok = true;
    if (grp == 0){ ww = w+1; ok = (ww < Ww); }
    else if (grp == 1){ ww = w-1; ok = (ww >= 0); }
    else if (grp == 2){ hh = h+1; ok = (hh < Hh); }
    else if (grp == 3){ hh = h-1; ok = (hh >= 0); }
    float yv = ok ? Yb[e*HW + hh*Ww + ww] : 0.f;
    #pragma unroll
    for (int c4 = 0; c4 < 15; c4++){
      float4 wv = wT4[e*15 + c4];
      acc[4*c4]   += wv.x*yv;
      acc[4*c4+1] += wv.y*yv;
      acc[4*c4+2] += wv.z*yv;
      acc[4*c4+3] += wv.w*yv;
    }
  }
  const float* Rp = R + (size_t)b*(Cdim*HW) + hw;
  float* Xp = X + (size_t)b*(Cdim*HW) + hw;
  #pragma unroll
  for (int c = 0; c < Cdim; c++){
    Xp[c*HW] = acc[c] + bL[c] + Rp[c*HW];
  }
}

// ---------------- WSA stage 1: t = BN(conv1x1(x, pi_w, pi_b)) -- BN folded ----------------
__global__ __launch_bounds__(256) void k_wsat(const float* __restrict__ X, float* __restrict__ T,
                                              fp piw, fp pib, fp g, fp bt, fp m, fp v){
  __shared__ __align__(16) float wL[Cdim*Cdim];
  __shared__ float cL[Cdim];
  int tid = threadIdx.x;
  for (int i = tid; i < Cdim*Cdim; i += 256){
    int o = i / Cdim;
    float a = g[o] * rsqrtf(v[o] + 1e-5f);
    wL[i] = piw[i] * a;
  }
  if (tid < Cdim){
    float a = g[tid] * rsqrtf(v[tid] + 1e-5f);
    cL[tid] = (pib[tid] - m[tid])*a + bt[tid];
  }
  __syncthreads();
  int p = blockIdx.x*256 + tid;
  int b = p >> 16; int hw = p & 65535;
  const float* Xb = X + (size_t)b*(Cdim*HW) + hw;
  float xs[Cdim];
  #pragma unroll
  for (int c = 0; c < Cdim; c++) xs[c] = Xb[c*HW];
  const float4* wL4 = (const float4*)wL;
  float* Tb = T + (size_t)b*(Cdim*HW) + hw;
  #pragma unroll 2
  for (int o = 0; o < Cdim; o++){
    float acc = cL[o];
    #pragma unroll
    for (int c4 = 0; c4 < 15; c4++){
      float4 wv = wL4[o*15 + c4];
      acc += wv.x*xs[4*c4] + wv.y*xs[4*c4+1] + wv.z*xs[4*c4+2] + wv.w*xs[4*c4+3];
    }
    Tb[o*HW] = acc;
  }
}

// ---------------- WSA stage 2: windowed attention ----------------
// block = one window (b,i,j), 256 threads.
__global__ __launch_bounds__(256) void k_attn(const float* __restrict__ T, float* __restrict__ Y,
                                              fp mw, fp mb){
  __shared__ __align__(16) float mwT[Cdim*Cdim];  // [k][c]
  __shared__ float mbL[Cdim];
  __shared__ float qL[64*61];
  __shared__ float vL[64*61];
  __shared__ float sL[64*65];       // reused: subL[k*64+p] first, then scores
  int tid = threadIdx.x;
  for (int i = tid; i < Cdim*Cdim; i += 256){
    int k = i / Cdim, c = i - k*Cdim;
    mwT[i] = mw[c*Cdim + k];
  }
  if (tid < Cdim) mbL[tid] = mb[tid];
  int blk = blockIdx.x;
  int b = blk >> 10; int ij = blk & 1023; int wi = ij >> 5; int wj = ij & 31;
  const float* Tb = T + (size_t)b*(Cdim*HW);
  // stage sub (stride-2 sampled, transposed, dup-edge-padded): subL[k*64+p]
  for (int idx = tid; idx < Cdim*64; idx += 256){
    int k = idx >> 6, p = idx & 63;
    int u = p >> 3, vq = p & 7;       // u = col-sample index, vq = row-sample index
    int r  = wi*8 + 2*vq; if (r > 255) r -= 8;
    int cc = wj*8 + 2*u;  if (cc > 255) cc -= 8;
    sL[idx] = Tb[k*HW + r*Ww + cc];
  }
  // stage v tokens: vL[p*61+c], p = row*8+col
  {
    int p = tid & 63; int cg = tid >> 6;
    int pr = p >> 3, pc = p & 7;
    const float* base = Tb + (wi*8+pr)*Ww + (wj*8+pc);
    #pragma unroll
    for (int t2 = 0; t2 < 15; t2++)
      vL[p*61 + cg*15 + t2] = base[(cg*15+t2)*HW];
  }
  __syncthreads();
  // q[p][c] = sum_k mw[c][k] * sub[k][p] + mb[c]
  {
    int p = tid & 63; int cg = tid >> 6;
    #pragma unroll 1
    for (int c = cg*15; c < cg*15+15; c++){
      float acc = mbL[c];
      #pragma unroll
      for (int k = 0; k < Cdim; k++)
        acc += mwT[k*Cdim + c] * sL[k*64 + p];
      qL[p*61 + c] = acc;
    }
  }
  __syncthreads();
  // scores s[p][q2] = <q_p, q_q2>
  {
    int p = tid & 63; int qg = tid >> 6;
    #pragma unroll 1
    for (int q2 = qg*16; q2 < qg*16+16; q2++){
      float acc = 0.f;
      #pragma unroll
      for (int c = 0; c < Cdim; c++)
        acc += qL[p*61 + c] * qL[q2*61 + c];
      sL[p*65 + q2] = acc;
    }
  }
  __syncthreads();
  // softmax rows (one row per lane of first wave)
  if (tid < 64){
    float mx = -1e30f;
    #pragma unroll
    for (int q2 = 0; q2 < 64; q2++) mx = fmaxf(mx, sL[tid*65+q2]);
    float sum = 0.f;
    #pragma unroll
    for (int q2 = 0; q2 < 64; q2++){ float e = __expf(sL[tid*65+q2]-mx); sL[tid*65+q2] = e; sum += e; }
    float inv = 1.f/sum;
    #pragma unroll
    for (int q2 = 0; q2 < 64; q2++) sL[tid*65+q2] *= inv;
  }
  __syncthreads();
  // y = atn @ v, store to Y[b][c][h][w]
  {
    int p = tid & 63; int cg = tid >> 6;
    int pr = p >> 3, pc = p & 7;
    float acc[15];
    #pragma unroll
    for (int t2 = 0; t2 < 15; t2++) acc[t2] = 0.f;
    #pragma unroll 1
    for (int q2 = 0; q2 < 64; q2++){
      float a = sL[p*65 + q2];
      #pragma unroll
      for (int t2 = 0; t2 < 15; t2++)
        acc[t2] += a * vL[q2*61 + cg*15 + t2];
    }
    float* Yb = Y + (size_t)b*(Cdim*HW) + (wi*8+pr)*Ww + (wj*8+pc);
    #pragma unroll
    for (int t2 = 0; t2 < 15; t2++)
      Yb[(cg*15+t2)*HW] = acc[t2];
  }
}

// ---------------- WSA stage 3: X = conv1x1(y, po) + X (in place) ----------------
__global__ __launch_bounds__(256) void k_wsaout(const float* __restrict__ Y, float* __restrict__ X,
                                                fp pw, fp pb){
  __shared__ __align__(16) float wL[Cdim*Cdim];
  __shared__ float bL[Cdim];
  int tid = threadIdx.x;
  for (int i = tid; i < Cdim*Cdim; i += 256) wL[i] = pw[i];
  if (tid < Cdim) bL[tid] = pb[tid];
  __syncthreads();
  int p = blockIdx.x*256 + tid;
  int b = p >> 16; int hw = p & 65535;
  const float* Yb = Y + (size_t)b*(Cdim*HW) + hw;
  float ys[Cdim];
  #pragma unroll
  for (int c = 0; c < Cdim; c++) ys[c] = Yb[c*HW];
  const float4* wL4 = (const float4*)wL;
  float* Xp = X + (size_t)b*(Cdim*HW) + hw;
  #pragma unroll 2
  for (int o = 0; o < Cdim; o++){
    float acc = bL[o];
    #pragma unroll
    for (int c4 = 0; c4 < 15; c4++){
      float4 wv = wL4[o*15 + c4];
      acc += wv.x*ys[4*c4] + wv.y*ys[4*c4+1] + wv.z*ys[4*c4+2] + wv.w*ys[4*c4+3];
    }
    Xp[o*HW] = acc + Xp[o*HW];
  }
}

extern "C" void kernel_launch(void* const* d_in, const int* in_sizes, int n_in,
                              void* d_out, int out_size, void* d_ws, size_t ws_size,
                              hipStream_t stream){
  fp x      = (fp)d_in[0];
  fp lfe_w0 = (fp)d_in[1];
  fp lfe_b0 = (fp)d_in[2];
  fp lfe_w1 = (fp)d_in[3];
  fp lfe_b1 = (fp)d_in[4];
  fp pi_w   = (fp)d_in[5];
  fp pi_b   = (fp)d_in[6];
  fp bn_g   = (fp)d_in[7];
  fp bn_b   = (fp)d_in[8];
  fp bn_m   = (fp)d_in[9];
  fp bn_v   = (fp)d_in[10];
  fp mask_w = (fp)d_in[11];
  fp mask_b = (fp)d_in[12];
  fp po_w   = (fp)d_in[13];
  fp po_b   = (fp)d_in[14];

  const size_t XSZ = (size_t)Bn*Cdim*HW;     // 15,728,640 floats (63 MB)
  float* X  = (float*)d_out;                 // residual stream lives in d_out (fp32)
  float* Y1 = (float*)d_ws;                  // [0, 2*XSZ): 120-ch LFE intermediate
  float* T  = Y1;                            // [0, XSZ): t-tensor (Y1 dead by then)
  float* Yw = Y1 + XSZ;                      // [XSZ, 2*XSZ): attention output

  for (int d = 0; d < 2; d++){
    fp src = (d == 0) ? x : X;               // depth-0 reads the input directly
    k_lfe1  <<<NPIX/256, 256, 0, stream>>>(src, Y1, lfe_w0 + d*Ce*Cdim, lfe_b0 + d*Ce);
    k_lfe2  <<<NPIX/256, 256, 0, stream>>>(Y1, src, X, lfe_w1 + d*Ce*Cdim, lfe_b1 + d*Cdim);
    k_wsat  <<<NPIX/256, 256, 0, stream>>>(X, T, pi_w + d*Cdim*Cdim, pi_b + d*Cdim,
                                           bn_g + d*Cdim, bn_b + d*Cdim, bn_m + d*Cdim, bn_v + d*Cdim);
    k_attn  <<<Bn*32*32, 256, 0, stream>>>(T, Yw, mask_w + d*Cdim*Cdim, mask_b + d*Cdim);
    k_wsaout<<<NPIX/256, 256, 0, stream>>>(Yw, X, po_w + d*Cdim*Cdim, po_b + d*Cdim);
  }
}